// Round 5
// baseline (112.113 us; speedup 1.0000x reference)
//
#include <hip/hip_runtime.h>
#include <math.h>

#define CCH 256
#define HW  9216
#define CW  24576
#define TWO_PI 6.28318530717958647692f
#define NQBLK 144u

typedef __attribute__((ext_vector_type(8))) short short8;
typedef __attribute__((ext_vector_type(4))) float f32x4;

__device__ inline unsigned short f2bf(float f) {
    unsigned u = __float_as_uint(f);
    unsigned r = (u + 0x7FFFu + ((u >> 16) & 1u)) >> 16;   // RNE
    return (unsigned short)r;
}

// ---------------- K_pre: fused {per-channel DFT + FQm zero} and {weight conversion} ----------------
// blocks [0,256):  channel c = bid: |x| minmax + 16 DFT coefficients -> Fg; zero FQm slice
// blocks [256,320): Wq/Wv -> bf16 tiles [ot][kc][m]
__global__ __launch_bounds__(768) void k_pre(const float* __restrict__ x,
                                             const float* __restrict__ Wq,
                                             const float* __restrict__ Wv,
                                             short8* __restrict__ Wqt,
                                             short8* __restrict__ Wvt,
                                             unsigned* __restrict__ FQm,
                                             float* __restrict__ Fg,
                                             unsigned* __restrict__ qdone) {
    __shared__ float qa[HW];         // 36 KB |x|
    __shared__ float cs[96][2];
    __shared__ float Gp[8][96][5];
    __shared__ float Gs[96][6];
    __shared__ float red[24];
    __shared__ float s_mn, s_ptp;
    int bid = blockIdx.x, t = threadIdx.x;

    if (bid >= 256) {                // weight-conversion blocks
        int widx = bid - 256;        // 0..63
        if (t < 256) {
            const float* src = (widx >= 32) ? Wv : Wq;
            short8* dst = (widx >= 32) ? Wvt : Wqt;
            int cidx = (widx & 31) * 256 + t;             // 0..8191
            int ot = cidx >> 11, kc = (cidx >> 6) & 31, m = cidx & 63;
            const float* s = src + (ot * 64 + m) * 256 + kc * 8;
            short8 v;
            #pragma unroll
            for (int e = 0; e < 8; ++e) v[e] = (short)f2bf(s[e]);
            dst[cidx] = v;
        }
        return;
    }

    int c = bid;
    if (t < 96) FQm[c * 96 + t] = 0u;   // zero FQm (24576 words over 256 blocks)
    if (bid == 0 && t == 96) *qdone = 0u;   // zero the Q-completion counter
    const float* xp = x + c * HW;
    if (t < 96) { float a = TWO_PI * (float)t / 96.0f; cs[t][0] = cosf(a); cs[t][1] = sinf(a); }
    float lo = 1e30f, hi = 0.f;
    #pragma unroll
    for (int i = 0; i < 12; ++i) {
        float a = fabsf(xp[t + i * 768]);
        qa[t + i * 768] = a;
        lo = fminf(lo, a);
        hi = fmaxf(hi, a);
    }
    #pragma unroll
    for (int d = 32; d; d >>= 1) {
        lo = fminf(lo, __shfl_xor(lo, d, 64));
        hi = fmaxf(hi, __shfl_xor(hi, d, 64));
    }
    if ((t & 63) == 0) { red[t >> 6] = lo; red[12 + (t >> 6)] = hi; }
    __syncthreads();
    if (t == 0) {
        lo = red[0]; hi = red[12];
        #pragma unroll
        for (int i = 1; i < 12; ++i) { lo = fminf(lo, red[i]); hi = fmaxf(hi, red[12 + i]); }
        s_mn = lo; s_ptp = hi - lo;
    }
    __syncthreads();
    float mn = s_mn, ptp = s_ptp;

    // Phase A: thread (xx = t%96, h = t/96) sums 12 rows of the column DFT from LDS
    {
        int xx = t % 96, h = t / 96;
        float g0r = 0, g0i = 0, g1r = 0, g1i = 0, g2 = 0;
        for (int y = h * 12; y < h * 12 + 12; ++y) {
            float q = floorf(255.0f * (qa[y * 96 + xx] - mn) / ptp);
            float c1 = cs[y][0], s1 = cs[y][1];
            float c2 = c1 * c1 - s1 * s1, s2 = 2.0f * c1 * s1;
            g0r += q * c2; g0i += q * s2;   // k=-2: e^{+2iθ}
            g1r += q * c1; g1i += q * s1;   // k=-1: e^{+iθ}
            g2  += q;                       // k=0
        }
        Gp[h][xx][0] = g0r; Gp[h][xx][1] = g0i;
        Gp[h][xx][2] = g1r; Gp[h][xx][3] = g1i;
        Gp[h][xx][4] = g2;
    }
    __syncthreads();
    if (t < 96) {
        #pragma unroll
        for (int j = 0; j < 5; ++j) {
            float s = 0.f;
            #pragma unroll
            for (int h = 0; h < 8; ++h) s += Gp[h][t][j];
            Gs[t][j] = s;
        }
        Gs[t][5] = 0.f;
    }
    __syncthreads();
    if (t < 64) {
        int coef = t >> 2, qq = t & 3;
        int ky = coef >> 2, kx = coef & 3;
        float fr = 0, fi = 0;
        for (int xx = qq * 24; xx < qq * 24 + 24; ++xx) {
            float c1 = cs[xx][0], s1 = cs[xx][1];
            float er, ei;
            if (kx == 0)      { er = c1 * c1 - s1 * s1; ei = 2.0f * c1 * s1; }
            else if (kx == 1) { er = c1; ei = s1; }
            else if (kx == 2) { er = 1.f; ei = 0.f; }
            else              { er = c1; ei = -s1; }
            float gr, gi;
            if (ky == 0)      { gr = Gs[xx][0]; gi = Gs[xx][1]; }
            else if (ky == 1) { gr = Gs[xx][2]; gi = Gs[xx][3]; }
            else if (ky == 2) { gr = Gs[xx][4]; gi = 0.f; }
            else              { gr = Gs[xx][2]; gi = -Gs[xx][3]; }
            fr += gr * er - gi * ei;
            fi += gr * ei + gi * er;
        }
        fr += __shfl_xor(fr, 1, 64); fr += __shfl_xor(fr, 2, 64);
        fi += __shfl_xor(fi, 1, 64); fi += __shfl_xor(fi, 2, 64);
        if (qq == 0) {
            Fg[c * 32 + 2 * coef]     = fr;
            Fg[c * 32 + 2 * coef + 1] = fi;
        }
    }
}

// ---------------- K_gemmQV: grid (144, 3), single launch, Q||V overlap + fused mask.
// y==0 : Q — all 4 ot tiles folded; Rs/Bs synthesized once; T-table (aliased on As)
//        kills per-element sincos; colmax in regs; 512 atomics -> FQm; then release
//        increment of qdone.
// y>=1 : V — ot pair {2(y-1), 2(y-1)+1}; gather Bs once; both MFMA tile-sets kept in
//        registers; acquire spin on qdone==144 ONLY at the epilogue; decode mask; write.
// 80 KB LDS both paths -> 2 blocks/CU -> 432 blocks <= 512 resident slots: no deadlock.
__device__ inline float mdecode(unsigned key) {
    unsigned ub = (key & 0x80000000u) ? (key ^ 0x80000000u) : ~key;
    return __uint_as_float(ub);
}
__global__ __launch_bounds__(256) void k_gemmQV(const short8* __restrict__ Wqt,
                                                const short8* __restrict__ Wvt,
                                                const float* __restrict__ Fg,
                                                const float* __restrict__ bq,
                                                const float* __restrict__ bv,
                                                const float* __restrict__ x,
                                                unsigned* __restrict__ FQm,
                                                float* __restrict__ out,
                                                unsigned* __restrict__ qdone) {
    __shared__ short8 As[2048];     // 32 KB [kc][m]   (Q: T-table aliases until MFMA loop)
    __shared__ short8 Bs[2048];     // 32 KB [kc][n]
    __shared__ float Rs[2048][2];   // 16 KB (Q-path; fq aliases it after B-synth)
    float (*fq)[64] = (float (*)[64])Rs;   // 8x64 = 2 KB staging for atomic combine
    float (*Ts)[9]  = (float (*)[9])As;    // 64x9 floats = 2.25 KB, dead before MFMA loop
    int tid = threadIdx.x;
    int pt_ = blockIdx.x;
    int p0 = pt_ * 64;

    int l = tid & 63, w = tid >> 6;
    int wr = w >> 1, wc = w & 1;
    int l15 = l & 15, quad = l >> 4;
    int abase = wr * 32 + l15;
    int bbase = wc * 32 + l15;

    if (blockIdx.y == 0) {
        // ================= Q path =================
        short8 areg[8];
        #pragma unroll
        for (int i = 0; i < 8; ++i) areg[i] = Wqt[i * 256 + tid];

        int y0 = p0 / 96;
        // T-table: 64 distinct xx values for this block's p-range (identical cosf bits)
        if (tid < 64) {
            int xx = (p0 + tid) % 96;
            float axv = TWO_PI * (float)xx / 96.0f;
            float cxv = cosf(axv), sxv = sinf(axv);
            float cx2 = cxv * cxv - sxv * sxv, sx2 = 2.f * cxv * sxv;
            Ts[tid][0] = cx2;  Ts[tid][1] = cxv;  Ts[tid][2] = 1.f; Ts[tid][3] = cxv;
            Ts[tid][4] = -sx2; Ts[tid][5] = -sxv; Ts[tid][6] = 0.f; Ts[tid][7] = sxv;
        }
        // R[c][yi][kx] = sum_ky F[c][ky][kx] * U[ky](y0+yi)
        {
            int yi = (tid >> 2) & 1, kx = tid & 3, cb = tid >> 3;
            float ay = TWO_PI * (float)(y0 + yi) / 96.0f;
            float cyv = cosf(ay), syv = sinf(ay);
            float cy2 = cyv * cyv - syv * syv, sy2 = 2.f * cyv * syv;
            float Ur[4] = { cy2, cyv, 1.f, cyv };
            float Ui[4] = { -sy2, -syv, 0.f, syv };
            #pragma unroll
            for (int i = 0; i < 8; ++i) {
                int cc = cb + i * 32;
                float rr = 0.f, ri = 0.f;
                #pragma unroll
                for (int ky = 0; ky < 4; ++ky) {
                    float fr = Fg[cc * 32 + 2 * (ky * 4 + kx)];
                    float fi = Fg[cc * 32 + 2 * (ky * 4 + kx) + 1];
                    rr += fr * Ur[ky] - fi * Ui[ky];
                    ri += fr * Ui[ky] + fi * Ur[ky];
                }
                Rs[cc * 8 + yi * 4 + kx][0] = rr;
                Rs[cc * 8 + yi * 4 + kx][1] = ri;
            }
        }
        __syncthreads();   // Rs + Ts ready
        // Bs[kc][n] = f2bf(|sum_kx R[c][yi(n)][kx] * T[kx](x(n))| / 9216)  — ONCE
        const float inv = 1.0f / 9216.0f;
        #pragma unroll
        for (int i = 0; i < 8; ++i) {
            int si = i * 256 + tid;
            int kcg = si >> 6, n = si & 63;
            int p = p0 + n;
            int y = p / 96;
            int yi = y - y0;
            float Tr[4], Ti[4];
            #pragma unroll
            for (int j = 0; j < 4; ++j) { Tr[j] = Ts[n][j]; Ti[j] = Ts[n][4 + j]; }
            short8 vv;
            #pragma unroll
            for (int e = 0; e < 8; ++e) {
                int rb = (kcg * 8 + e) * 8 + yi * 4;
                float ar = 0.f, ai = 0.f;
                #pragma unroll
                for (int kx = 0; kx < 4; ++kx) {
                    float rr = Rs[rb + kx][0], ri = Rs[rb + kx][1];
                    ar += rr * Tr[kx] - ri * Ti[kx];
                    ai += rr * Ti[kx] + ri * Tr[kx];
                }
                vv[e] = (short)f2bf(sqrtf(ar * ar + ai * ai) * inv);
            }
            Bs[si] = vv;
        }
        __syncthreads();   // Bs ready; Rs and Ts dead from here (fq / As may alias)

        float vmax[2][4];
        #pragma unroll
        for (int ni = 0; ni < 2; ++ni)
            #pragma unroll
            for (int r = 0; r < 4; ++r) vmax[ni][r] = -3.0e38f;

        #pragma unroll
        for (int ot = 0; ot < 4; ++ot) {
            #pragma unroll
            for (int i = 0; i < 8; ++i) As[i * 256 + tid] = areg[i];
            __syncthreads();
            if (ot < 3) {          // prefetch next As tile; L2-hot, hides under MFMA
                #pragma unroll
                for (int i = 0; i < 8; ++i) areg[i] = Wqt[(ot + 1) * 2048 + i * 256 + tid];
            }
            f32x4 acc[2][2] = {};
            #pragma unroll
            for (int s = 0; s < 8; ++s) {
                int kc = s * 4 + quad;
                short8 a0 = As[kc * 64 + abase];
                short8 a1 = As[kc * 64 + abase + 16];
                short8 b0 = Bs[kc * 64 + bbase];
                short8 b1 = Bs[kc * 64 + bbase + 16];
                acc[0][0] = __builtin_amdgcn_mfma_f32_16x16x32_bf16(a0, b0, acc[0][0], 0, 0, 0);
                acc[0][1] = __builtin_amdgcn_mfma_f32_16x16x32_bf16(a0, b1, acc[0][1], 0, 0, 0);
                acc[1][0] = __builtin_amdgcn_mfma_f32_16x16x32_bf16(a1, b0, acc[1][0], 0, 0, 0);
                acc[1][1] = __builtin_amdgcn_mfma_f32_16x16x32_bf16(a1, b1, acc[1][1], 0, 0, 0);
            }
            // C/D layout: col = lane&15, row = quad*4 + reg; o&7 independent of ot/wr/mi
            #pragma unroll
            for (int ni = 0; ni < 2; ++ni) {
                #pragma unroll
                for (int r = 0; r < 4; ++r) {
                    int o_lo = ot * 64 + wr * 32 + quad * 4 + r;
                    float v = fmaxf(acc[0][ni][r] + bq[o_lo], acc[1][ni][r] + bq[o_lo + 16]);
                    vmax[ni][r] = fmaxf(vmax[ni][r], v);
                }
            }
            __syncthreads();       // all waves done reading As before next overwrite
        }

        // fold lane^32 (quad <-> quad+2 pairs share o&7), then wr pairs via LDS
        #pragma unroll
        for (int ni = 0; ni < 2; ++ni)
            #pragma unroll
            for (int r = 0; r < 4; ++r)
                vmax[ni][r] = fmaxf(vmax[ni][r], __shfl_xor(vmax[ni][r], 32, 64));
        if (wr == 0 && quad < 2) {
            #pragma unroll
            for (int ni = 0; ni < 2; ++ni)
                #pragma unroll
                for (int r = 0; r < 4; ++r)
                    fq[quad * 4 + r][wc * 32 + ni * 16 + l15] = vmax[ni][r];
        }
        __syncthreads();
        if (wr == 1 && quad < 2) {
            #pragma unroll
            for (int ni = 0; ni < 2; ++ni) {
                #pragma unroll
                for (int r = 0; r < 4; ++r) {
                    int row = quad * 4 + r;
                    int col = wc * 32 + ni * 16 + l15;
                    float v = fmaxf(vmax[ni][r], fq[row][col]);
                    int p = p0 + col;
                    int k = row * HW + p;
                    if (k >= CW) k -= CW;
                    if (k >= CW) k -= CW;
                    unsigned u = __float_as_uint(v);
                    unsigned key = (u & 0x80000000u) ? ~u : (u | 0x80000000u);
                    atomicMax(&FQm[k], key);
                }
            }
        }
        __syncthreads();           // drains every thread's atomics (vmcnt) before barrier
        if (tid == 0) {
            __threadfence();       // release
            atomicAdd(qdone, 1u);
        }
        return;
    }

    // ================= V path =================
    int yv = blockIdx.y - 1;       // 0..1 -> ot pair {2yv, 2yv+1}
    short8 areg[8];
    #pragma unroll
    for (int i = 0; i < 8; ++i) areg[i] = Wvt[(yv * 2) * 2048 + i * 256 + tid];

    // Bs[KC][n][e] = f2bf(x[(KC*8+e)*HW + p0+n]) — per-wave coalesced gather, ONCE
    #pragma unroll
    for (int i = 0; i < 8; ++i) {
        int si = i * 256 + tid;
        int KC = si >> 6, n = si & 63;
        const float* xb = x + (size_t)(KC * 8) * HW + p0 + n;
        short8 v;
        #pragma unroll
        for (int e = 0; e < 8; ++e) v[e] = (short)f2bf(xb[(size_t)e * HW]);
        Bs[si] = v;
    }
    #pragma unroll
    for (int i = 0; i < 8; ++i) As[i * 256 + tid] = areg[i];
    __syncthreads();               // As(j=0) + Bs ready
    #pragma unroll
    for (int i = 0; i < 8; ++i) areg[i] = Wvt[(yv * 2 + 1) * 2048 + i * 256 + tid];

    f32x4 accA[2][2] = {}, accB[2][2] = {};
    #pragma unroll
    for (int s = 0; s < 8; ++s) {
        int kc = s * 4 + quad;
        short8 a0 = As[kc * 64 + abase];
        short8 a1 = As[kc * 64 + abase + 16];
        short8 b0 = Bs[kc * 64 + bbase];
        short8 b1 = Bs[kc * 64 + bbase + 16];
        accA[0][0] = __builtin_amdgcn_mfma_f32_16x16x32_bf16(a0, b0, accA[0][0], 0, 0, 0);
        accA[0][1] = __builtin_amdgcn_mfma_f32_16x16x32_bf16(a0, b1, accA[0][1], 0, 0, 0);
        accA[1][0] = __builtin_amdgcn_mfma_f32_16x16x32_bf16(a1, b0, accA[1][0], 0, 0, 0);
        accA[1][1] = __builtin_amdgcn_mfma_f32_16x16x32_bf16(a1, b1, accA[1][1], 0, 0, 0);
    }
    __syncthreads();               // done reading As(j=0)
    #pragma unroll
    for (int i = 0; i < 8; ++i) As[i * 256 + tid] = areg[i];
    __syncthreads();               // As(j=1) ready
    #pragma unroll
    for (int s = 0; s < 8; ++s) {
        int kc = s * 4 + quad;
        short8 a0 = As[kc * 64 + abase];
        short8 a1 = As[kc * 64 + abase + 16];
        short8 b0 = Bs[kc * 64 + bbase];
        short8 b1 = Bs[kc * 64 + bbase + 16];
        accB[0][0] = __builtin_amdgcn_mfma_f32_16x16x32_bf16(a0, b0, accB[0][0], 0, 0, 0);
        accB[0][1] = __builtin_amdgcn_mfma_f32_16x16x32_bf16(a0, b1, accB[0][1], 0, 0, 0);
        accB[1][0] = __builtin_amdgcn_mfma_f32_16x16x32_bf16(a1, b0, accB[1][0], 0, 0, 0);
        accB[1][1] = __builtin_amdgcn_mfma_f32_16x16x32_bf16(a1, b1, accB[1][1], 0, 0, 0);
    }

    // --- acquire spin: all Q blocks done -> FQm complete ---
    if (tid == 0) {
        while (__hip_atomic_load(qdone, __ATOMIC_RELAXED, __HIP_MEMORY_SCOPE_AGENT) < NQBLK)
            __builtin_amdgcn_s_sleep(8);
        __threadfence();           // acquire
    }
    __syncthreads();               // compiler+exec barrier: FQm loads stay below

    float msk[2][4];
    #pragma unroll
    for (int ni = 0; ni < 2; ++ni) {
        #pragma unroll
        for (int r = 0; r < 4; ++r) {
            int row = (quad * 4 + r) & 7;
            int p = p0 + wc * 32 + ni * 16 + l15;
            int k = row * HW + p;
            if (k >= CW) k -= CW;
            if (k >= CW) k -= CW;
            msk[ni][r] = mdecode(FQm[k]);
        }
    }

    // C/D layout: col = lane&15, row = quad*4 + reg.  out = (V+bv)*(1+mask)
    #pragma unroll
    for (int j = 0; j < 2; ++j) {
        int ot = yv * 2 + j;
        #pragma unroll
        for (int mi = 0; mi < 2; ++mi) {
            #pragma unroll
            for (int ni = 0; ni < 2; ++ni) {
                #pragma unroll
                for (int r = 0; r < 4; ++r) {
                    int o = ot * 64 + wr * 32 + mi * 16 + quad * 4 + r;
                    int p = p0 + wc * 32 + ni * 16 + l15;
                    float a = j ? accB[mi][ni][r] : accA[mi][ni][r];
                    out[(size_t)o * HW + p] = (a + bv[o]) * (1.0f + msk[ni][r]);
                }
            }
        }
    }
}

extern "C" void kernel_launch(void* const* d_in, const int* in_sizes, int n_in,
                              void* d_out, int out_size, void* d_ws, size_t ws_size,
                              hipStream_t stream) {
    const float* fuse = (const float*)d_in[0];
    const float* Wq   = (const float*)d_in[1];
    const float* bq   = (const float*)d_in[2];
    // d_in[3]=Wk, d_in[4]=bk dead for B=1 (softmax over batch axis of size 1 == 1)
    const float* Wv   = (const float*)d_in[5];
    const float* bv   = (const float*)d_in[6];
    float* out = (float*)d_out;

    char* ws = (char*)d_ws;
    unsigned* FQm   = (unsigned*)(ws);            //  98304 B (zeroed by k_pre)
    float*    Fg    = (float*)(ws + 98304);       //  32768 B
    short8*   Wqt   = (short8*)(ws + 131072);     // 131072 B
    short8*   Wvt   = (short8*)(ws + 262144);     // 131072 B
    unsigned* qdone = (unsigned*)(ws + 393216);   //      4 B (zeroed by k_pre)

    k_pre<<<320, 768, 0, stream>>>(fuse, Wq, Wv, Wqt, Wvt, FQm, Fg, qdone);
    k_gemmQV<<<dim3(144, 3), 256, 0, stream>>>(Wqt, Wvt, Fg, bq, bv, fuse, FQm, out, qdone);
}

// Round 6
// 108.987 us; speedup vs baseline: 1.0287x; 1.0287x over previous
//
#include <hip/hip_runtime.h>
#include <math.h>

#define CCH 256
#define HW  9216
#define CW  24576
#define TWO_PI 6.28318530717958647692f
#define NQBLK 144u

typedef __attribute__((ext_vector_type(8))) short short8;
typedef __attribute__((ext_vector_type(4))) float f32x4;

__device__ inline unsigned short f2bf(float f) {
    unsigned u = __float_as_uint(f);
    unsigned r = (u + 0x7FFFu + ((u >> 16) & 1u)) >> 16;   // RNE
    return (unsigned short)r;
}

// ---------------- K_pre: fused {per-channel DFT + FQm zero} and {weight conversion} ----------------
// blocks [0,256):  channel c = bid: |x| minmax + 16 DFT coefficients -> Fg; zero FQm slice
// blocks [256,320): Wq/Wv -> bf16 tiles [ot][kc][m]
__global__ __launch_bounds__(768) void k_pre(const float* __restrict__ x,
                                             const float* __restrict__ Wq,
                                             const float* __restrict__ Wv,
                                             short8* __restrict__ Wqt,
                                             short8* __restrict__ Wvt,
                                             unsigned* __restrict__ FQm,
                                             float* __restrict__ Fg,
                                             unsigned* __restrict__ qdone) {
    __shared__ float qa[HW];         // 36 KB |x|
    __shared__ float cs[96][2];
    __shared__ float Gp[8][96][5];
    __shared__ float Gs[96][6];
    __shared__ float red[24];
    __shared__ float s_mn, s_ptp;
    int bid = blockIdx.x, t = threadIdx.x;

    if (bid >= 256) {                // weight-conversion blocks
        int widx = bid - 256;        // 0..63
        if (t < 256) {
            const float* src = (widx >= 32) ? Wv : Wq;
            short8* dst = (widx >= 32) ? Wvt : Wqt;
            int cidx = (widx & 31) * 256 + t;             // 0..8191
            int ot = cidx >> 11, kc = (cidx >> 6) & 31, m = cidx & 63;
            const float* s = src + (ot * 64 + m) * 256 + kc * 8;
            short8 v;
            #pragma unroll
            for (int e = 0; e < 8; ++e) v[e] = (short)f2bf(s[e]);
            dst[cidx] = v;
        }
        return;
    }

    int c = bid;
    if (t < 96) FQm[c * 96 + t] = 0u;   // zero FQm (24576 words over 256 blocks)
    if (bid == 0 && t == 96) *qdone = 0u;   // zero the Q-completion counter
    const float* xp = x + c * HW;
    if (t < 96) { float a = TWO_PI * (float)t / 96.0f; cs[t][0] = cosf(a); cs[t][1] = sinf(a); }
    float lo = 1e30f, hi = 0.f;
    #pragma unroll
    for (int i = 0; i < 12; ++i) {
        float a = fabsf(xp[t + i * 768]);
        qa[t + i * 768] = a;
        lo = fminf(lo, a);
        hi = fmaxf(hi, a);
    }
    #pragma unroll
    for (int d = 32; d; d >>= 1) {
        lo = fminf(lo, __shfl_xor(lo, d, 64));
        hi = fmaxf(hi, __shfl_xor(hi, d, 64));
    }
    if ((t & 63) == 0) { red[t >> 6] = lo; red[12 + (t >> 6)] = hi; }
    __syncthreads();
    if (t == 0) {
        lo = red[0]; hi = red[12];
        #pragma unroll
        for (int i = 1; i < 12; ++i) { lo = fminf(lo, red[i]); hi = fmaxf(hi, red[12 + i]); }
        s_mn = lo; s_ptp = hi - lo;
    }
    __syncthreads();
    float mn = s_mn, ptp = s_ptp;

    // Phase A: thread (xx = t%96, h = t/96) sums 12 rows of the column DFT from LDS
    {
        int xx = t % 96, h = t / 96;
        float g0r = 0, g0i = 0, g1r = 0, g1i = 0, g2 = 0;
        for (int y = h * 12; y < h * 12 + 12; ++y) {
            float q = floorf(255.0f * (qa[y * 96 + xx] - mn) / ptp);
            float c1 = cs[y][0], s1 = cs[y][1];
            float c2 = c1 * c1 - s1 * s1, s2 = 2.0f * c1 * s1;
            g0r += q * c2; g0i += q * s2;   // k=-2: e^{+2iθ}
            g1r += q * c1; g1i += q * s1;   // k=-1: e^{+iθ}
            g2  += q;                       // k=0
        }
        Gp[h][xx][0] = g0r; Gp[h][xx][1] = g0i;
        Gp[h][xx][2] = g1r; Gp[h][xx][3] = g1i;
        Gp[h][xx][4] = g2;
    }
    __syncthreads();
    if (t < 96) {
        #pragma unroll
        for (int j = 0; j < 5; ++j) {
            float s = 0.f;
            #pragma unroll
            for (int h = 0; h < 8; ++h) s += Gp[h][t][j];
            Gs[t][j] = s;
        }
        Gs[t][5] = 0.f;
    }
    __syncthreads();
    if (t < 64) {
        int coef = t >> 2, qq = t & 3;
        int ky = coef >> 2, kx = coef & 3;
        float fr = 0, fi = 0;
        for (int xx = qq * 24; xx < qq * 24 + 24; ++xx) {
            float c1 = cs[xx][0], s1 = cs[xx][1];
            float er, ei;
            if (kx == 0)      { er = c1 * c1 - s1 * s1; ei = 2.0f * c1 * s1; }
            else if (kx == 1) { er = c1; ei = s1; }
            else if (kx == 2) { er = 1.f; ei = 0.f; }
            else              { er = c1; ei = -s1; }
            float gr, gi;
            if (ky == 0)      { gr = Gs[xx][0]; gi = Gs[xx][1]; }
            else if (ky == 1) { gr = Gs[xx][2]; gi = Gs[xx][3]; }
            else if (ky == 2) { gr = Gs[xx][4]; gi = 0.f; }
            else              { gr = Gs[xx][2]; gi = -Gs[xx][3]; }
            fr += gr * er - gi * ei;
            fi += gr * ei + gi * er;
        }
        fr += __shfl_xor(fr, 1, 64); fr += __shfl_xor(fr, 2, 64);
        fi += __shfl_xor(fi, 1, 64); fi += __shfl_xor(fi, 2, 64);
        if (qq == 0) {
            Fg[c * 32 + 2 * coef]     = fr;
            Fg[c * 32 + 2 * coef + 1] = fi;
        }
    }
}

// ---------------- K_gemmQV: grid (144, 3), single launch, Q||V overlap + fused mask.
// Cross-block communication is RMW-ONLY (coherence-point guaranteed; scoped plain/atomic
// loads proved stale-prone in R5 — 60 µs visibility stall):
//   release: Q atomicMax(FQm) ... syncthreads (vmcnt drain) ... threadfence ... atomicAdd(qdone)
//   acquire: V spins on atomicAdd(qdone,0) RMW; mask reads via atomicOr(FQm,0) RMW.
// 80 KB LDS both paths -> 2 blocks/CU -> 432 blocks <= 512 resident slots: no deadlock.
__device__ inline float mdecode(unsigned key) {
    unsigned ub = (key & 0x80000000u) ? (key ^ 0x80000000u) : ~key;
    return __uint_as_float(ub);
}
__global__ __launch_bounds__(256) void k_gemmQV(const short8* __restrict__ Wqt,
                                                const short8* __restrict__ Wvt,
                                                const float* __restrict__ Fg,
                                                const float* __restrict__ bq,
                                                const float* __restrict__ bv,
                                                const float* __restrict__ x,
                                                unsigned* __restrict__ FQm,
                                                float* __restrict__ out,
                                                unsigned* __restrict__ qdone) {
    __shared__ short8 As[2048];     // 32 KB [kc][m]   (Q: T-table aliases until MFMA loop)
    __shared__ short8 Bs[2048];     // 32 KB [kc][n]
    __shared__ float Rs[2048][2];   // 16 KB (Q: fq aliases after B-synth; V: mask stage)
    float (*fq)[64]   = (float (*)[64])Rs;   // 8x64 staging for atomic combine (Q)
    float (*mskS)[64] = (float (*)[64])Rs;   // 8x64 mask stage (V)
    float (*Ts)[9]    = (float (*)[9])As;    // 64x9 floats, dead before MFMA loop (Q)
    int tid = threadIdx.x;
    int pt_ = blockIdx.x;
    int p0 = pt_ * 64;

    int l = tid & 63, w = tid >> 6;
    int wr = w >> 1, wc = w & 1;
    int l15 = l & 15, quad = l >> 4;
    int abase = wr * 32 + l15;
    int bbase = wc * 32 + l15;

    if (blockIdx.y == 0) {
        // ================= Q path =================
        short8 areg[8];
        #pragma unroll
        for (int i = 0; i < 8; ++i) areg[i] = Wqt[i * 256 + tid];

        int y0 = p0 / 96;
        // T-table: 64 distinct xx values for this block's p-range (identical cosf bits)
        if (tid < 64) {
            int xx = (p0 + tid) % 96;
            float axv = TWO_PI * (float)xx / 96.0f;
            float cxv = cosf(axv), sxv = sinf(axv);
            float cx2 = cxv * cxv - sxv * sxv, sx2 = 2.f * cxv * sxv;
            Ts[tid][0] = cx2;  Ts[tid][1] = cxv;  Ts[tid][2] = 1.f; Ts[tid][3] = cxv;
            Ts[tid][4] = -sx2; Ts[tid][5] = -sxv; Ts[tid][6] = 0.f; Ts[tid][7] = sxv;
        }
        // R[c][yi][kx] = sum_ky F[c][ky][kx] * U[ky](y0+yi)
        {
            int yi = (tid >> 2) & 1, kx = tid & 3, cb = tid >> 3;
            float ay = TWO_PI * (float)(y0 + yi) / 96.0f;
            float cyv = cosf(ay), syv = sinf(ay);
            float cy2 = cyv * cyv - syv * syv, sy2 = 2.f * cyv * syv;
            float Ur[4] = { cy2, cyv, 1.f, cyv };
            float Ui[4] = { -sy2, -syv, 0.f, syv };
            #pragma unroll
            for (int i = 0; i < 8; ++i) {
                int cc = cb + i * 32;
                float rr = 0.f, ri = 0.f;
                #pragma unroll
                for (int ky = 0; ky < 4; ++ky) {
                    float fr = Fg[cc * 32 + 2 * (ky * 4 + kx)];
                    float fi = Fg[cc * 32 + 2 * (ky * 4 + kx) + 1];
                    rr += fr * Ur[ky] - fi * Ui[ky];
                    ri += fr * Ui[ky] + fi * Ur[ky];
                }
                Rs[cc * 8 + yi * 4 + kx][0] = rr;
                Rs[cc * 8 + yi * 4 + kx][1] = ri;
            }
        }
        __syncthreads();   // Rs + Ts ready
        // Bs[kc][n] = f2bf(|sum_kx R[c][yi(n)][kx] * T[kx](x(n))| / 9216)  — ONCE
        const float inv = 1.0f / 9216.0f;
        #pragma unroll
        for (int i = 0; i < 8; ++i) {
            int si = i * 256 + tid;
            int kcg = si >> 6, n = si & 63;
            int p = p0 + n;
            int y = p / 96;
            int yi = y - y0;
            float Tr[4], Ti[4];
            #pragma unroll
            for (int j = 0; j < 4; ++j) { Tr[j] = Ts[n][j]; Ti[j] = Ts[n][4 + j]; }
            short8 vv;
            #pragma unroll
            for (int e = 0; e < 8; ++e) {
                int rb = (kcg * 8 + e) * 8 + yi * 4;
                float ar = 0.f, ai = 0.f;
                #pragma unroll
                for (int kx = 0; kx < 4; ++kx) {
                    float rr = Rs[rb + kx][0], ri = Rs[rb + kx][1];
                    ar += rr * Tr[kx] - ri * Ti[kx];
                    ai += rr * Ti[kx] + ri * Tr[kx];
                }
                vv[e] = (short)f2bf(sqrtf(ar * ar + ai * ai) * inv);
            }
            Bs[si] = vv;
        }
        __syncthreads();   // Bs ready; Rs and Ts dead from here (fq / As may alias)

        float vmax[2][4];
        #pragma unroll
        for (int ni = 0; ni < 2; ++ni)
            #pragma unroll
            for (int r = 0; r < 4; ++r) vmax[ni][r] = -3.0e38f;

        #pragma unroll
        for (int ot = 0; ot < 4; ++ot) {
            #pragma unroll
            for (int i = 0; i < 8; ++i) As[i * 256 + tid] = areg[i];
            __syncthreads();
            if (ot < 3) {          // prefetch next As tile; L2-hot, hides under MFMA
                #pragma unroll
                for (int i = 0; i < 8; ++i) areg[i] = Wqt[(ot + 1) * 2048 + i * 256 + tid];
            }
            f32x4 acc[2][2] = {};
            #pragma unroll
            for (int s = 0; s < 8; ++s) {
                int kc = s * 4 + quad;
                short8 a0 = As[kc * 64 + abase];
                short8 a1 = As[kc * 64 + abase + 16];
                short8 b0 = Bs[kc * 64 + bbase];
                short8 b1 = Bs[kc * 64 + bbase + 16];
                acc[0][0] = __builtin_amdgcn_mfma_f32_16x16x32_bf16(a0, b0, acc[0][0], 0, 0, 0);
                acc[0][1] = __builtin_amdgcn_mfma_f32_16x16x32_bf16(a0, b1, acc[0][1], 0, 0, 0);
                acc[1][0] = __builtin_amdgcn_mfma_f32_16x16x32_bf16(a1, b0, acc[1][0], 0, 0, 0);
                acc[1][1] = __builtin_amdgcn_mfma_f32_16x16x32_bf16(a1, b1, acc[1][1], 0, 0, 0);
            }
            // C/D layout: col = lane&15, row = quad*4 + reg; o&7 independent of ot/wr/mi
            #pragma unroll
            for (int ni = 0; ni < 2; ++ni) {
                #pragma unroll
                for (int r = 0; r < 4; ++r) {
                    int o_lo = ot * 64 + wr * 32 + quad * 4 + r;
                    float v = fmaxf(acc[0][ni][r] + bq[o_lo], acc[1][ni][r] + bq[o_lo + 16]);
                    vmax[ni][r] = fmaxf(vmax[ni][r], v);
                }
            }
            __syncthreads();       // all waves done reading As before next overwrite
        }

        // fold lane^32 (quad <-> quad+2 pairs share o&7), then wr pairs via LDS
        #pragma unroll
        for (int ni = 0; ni < 2; ++ni)
            #pragma unroll
            for (int r = 0; r < 4; ++r)
                vmax[ni][r] = fmaxf(vmax[ni][r], __shfl_xor(vmax[ni][r], 32, 64));
        if (wr == 0 && quad < 2) {
            #pragma unroll
            for (int ni = 0; ni < 2; ++ni)
                #pragma unroll
                for (int r = 0; r < 4; ++r)
                    fq[quad * 4 + r][wc * 32 + ni * 16 + l15] = vmax[ni][r];
        }
        __syncthreads();
        if (wr == 1 && quad < 2) {
            #pragma unroll
            for (int ni = 0; ni < 2; ++ni) {
                #pragma unroll
                for (int r = 0; r < 4; ++r) {
                    int row = quad * 4 + r;
                    int col = wc * 32 + ni * 16 + l15;
                    float v = fmaxf(vmax[ni][r], fq[row][col]);
                    int p = p0 + col;
                    int k = row * HW + p;
                    if (k >= CW) k -= CW;
                    if (k >= CW) k -= CW;
                    unsigned u = __float_as_uint(v);
                    unsigned key = (u & 0x80000000u) ? ~u : (u | 0x80000000u);
                    atomicMax(&FQm[k], key);
                }
            }
        }
        __syncthreads();           // drains every wave's atomics (vmcnt) before barrier
        if (tid == 0) {
            __threadfence();       // release
            atomicAdd(qdone, 1u);
        }
        return;
    }

    // ================= V path =================
    int yv = blockIdx.y - 1;       // 0..1 -> ot pair {2yv, 2yv+1}
    short8 areg[8];
    #pragma unroll
    for (int i = 0; i < 8; ++i) areg[i] = Wvt[(yv * 2) * 2048 + i * 256 + tid];

    // Bs[KC][n][e] = f2bf(x[(KC*8+e)*HW + p0+n]) — per-wave coalesced gather, ONCE
    #pragma unroll
    for (int i = 0; i < 8; ++i) {
        int si = i * 256 + tid;
        int KC = si >> 6, n = si & 63;
        const float* xb = x + (size_t)(KC * 8) * HW + p0 + n;
        short8 v;
        #pragma unroll
        for (int e = 0; e < 8; ++e) v[e] = (short)f2bf(xb[(size_t)e * HW]);
        Bs[si] = v;
    }
    #pragma unroll
    for (int i = 0; i < 8; ++i) As[i * 256 + tid] = areg[i];
    __syncthreads();               // As(j=0) + Bs ready
    #pragma unroll
    for (int i = 0; i < 8; ++i) areg[i] = Wvt[(yv * 2 + 1) * 2048 + i * 256 + tid];

    f32x4 accA[2][2] = {}, accB[2][2] = {};
    #pragma unroll
    for (int s = 0; s < 8; ++s) {
        int kc = s * 4 + quad;
        short8 a0 = As[kc * 64 + abase];
        short8 a1 = As[kc * 64 + abase + 16];
        short8 b0 = Bs[kc * 64 + bbase];
        short8 b1 = Bs[kc * 64 + bbase + 16];
        accA[0][0] = __builtin_amdgcn_mfma_f32_16x16x32_bf16(a0, b0, accA[0][0], 0, 0, 0);
        accA[0][1] = __builtin_amdgcn_mfma_f32_16x16x32_bf16(a0, b1, accA[0][1], 0, 0, 0);
        accA[1][0] = __builtin_amdgcn_mfma_f32_16x16x32_bf16(a1, b0, accA[1][0], 0, 0, 0);
        accA[1][1] = __builtin_amdgcn_mfma_f32_16x16x32_bf16(a1, b1, accA[1][1], 0, 0, 0);
    }
    __syncthreads();               // done reading As(j=0)
    #pragma unroll
    for (int i = 0; i < 8; ++i) As[i * 256 + tid] = areg[i];
    __syncthreads();               // As(j=1) ready
    #pragma unroll
    for (int s = 0; s < 8; ++s) {
        int kc = s * 4 + quad;
        short8 a0 = As[kc * 64 + abase];
        short8 a1 = As[kc * 64 + abase + 16];
        short8 b0 = Bs[kc * 64 + bbase];
        short8 b1 = Bs[kc * 64 + bbase + 16];
        accB[0][0] = __builtin_amdgcn_mfma_f32_16x16x32_bf16(a0, b0, accB[0][0], 0, 0, 0);
        accB[0][1] = __builtin_amdgcn_mfma_f32_16x16x32_bf16(a0, b1, accB[0][1], 0, 0, 0);
        accB[1][0] = __builtin_amdgcn_mfma_f32_16x16x32_bf16(a1, b0, accB[1][0], 0, 0, 0);
        accB[1][1] = __builtin_amdgcn_mfma_f32_16x16x32_bf16(a1, b1, accB[1][1], 0, 0, 0);
    }

    // --- acquire spin: RMW read (coherence-point; immune to stale L1/L2 lines) ---
    if (tid == 0) {
        while (atomicAdd(qdone, 0u) < NQBLK)
            __builtin_amdgcn_s_sleep(32);
    }
    __syncthreads();               // all FQm RMWs by Q are committed before this point

    // mask stage: 64 threads x 8 rows via RMW-read, into LDS (Rs region, dead in V path)
    if (tid < 64) {
        #pragma unroll
        for (int row = 0; row < 8; ++row) {
            int k = row * HW + p0 + tid;
            if (k >= CW) k -= CW;
            if (k >= CW) k -= CW;
            mskS[row][tid] = mdecode(atomicOr(&FQm[k], 0u));
        }
    }
    __syncthreads();

    float msk[2][4];
    #pragma unroll
    for (int ni = 0; ni < 2; ++ni)
        #pragma unroll
        for (int r = 0; r < 4; ++r)
            msk[ni][r] = mskS[(quad * 4 + r) & 7][wc * 32 + ni * 16 + l15];

    // C/D layout: col = lane&15, row = quad*4 + reg.  out = (V+bv)*(1+mask)
    #pragma unroll
    for (int j = 0; j < 2; ++j) {
        int ot = yv * 2 + j;
        #pragma unroll
        for (int mi = 0; mi < 2; ++mi) {
            #pragma unroll
            for (int ni = 0; ni < 2; ++ni) {
                #pragma unroll
                for (int r = 0; r < 4; ++r) {
                    int o = ot * 64 + wr * 32 + mi * 16 + quad * 4 + r;
                    int p = p0 + wc * 32 + ni * 16 + l15;
                    float a = j ? accB[mi][ni][r] : accA[mi][ni][r];
                    out[(size_t)o * HW + p] = (a + bv[o]) * (1.0f + msk[ni][r]);
                }
            }
        }
    }
}

extern "C" void kernel_launch(void* const* d_in, const int* in_sizes, int n_in,
                              void* d_out, int out_size, void* d_ws, size_t ws_size,
                              hipStream_t stream) {
    const float* fuse = (const float*)d_in[0];
    const float* Wq   = (const float*)d_in[1];
    const float* bq   = (const float*)d_in[2];
    // d_in[3]=Wk, d_in[4]=bk dead for B=1 (softmax over batch axis of size 1 == 1)
    const float* Wv   = (const float*)d_in[5];
    const float* bv   = (const float*)d_in[6];
    float* out = (float*)d_out;

    char* ws = (char*)d_ws;
    unsigned* FQm   = (unsigned*)(ws);            //  98304 B (zeroed by k_pre)
    float*    Fg    = (float*)(ws + 98304);       //  32768 B
    short8*   Wqt   = (short8*)(ws + 131072);     // 131072 B
    short8*   Wvt   = (short8*)(ws + 262144);     // 131072 B
    unsigned* qdone = (unsigned*)(ws + 393216);   //      4 B (zeroed by k_pre)

    k_pre<<<320, 768, 0, stream>>>(fuse, Wq, Wv, Wqt, Wvt, FQm, Fg, qdone);
    k_gemmQV<<<dim3(144, 3), 256, 0, stream>>>(Wqt, Wvt, Fg, bq, bv, fuse, FQm, out, qdone);
}

// Round 7
// 103.518 us; speedup vs baseline: 1.0830x; 1.0528x over previous
//
#include <hip/hip_runtime.h>
#include <math.h>

#define CCH 256
#define HW  9216
#define CW  24576
#define TWO_PI 6.28318530717958647692f

typedef __attribute__((ext_vector_type(8))) short short8;
typedef __attribute__((ext_vector_type(4))) float f32x4;

__device__ inline unsigned short f2bf(float f) {
    unsigned u = __float_as_uint(f);
    unsigned r = (u + 0x7FFFu + ((u >> 16) & 1u)) >> 16;   // RNE
    return (unsigned short)r;
}

// ---------------- K_pre: fused {per-channel DFT + FQm zero} and {weight conversion} ----------------
// blocks [0,256):  channel c = bid: |x| minmax + 16 DFT coefficients -> Fg; zero FQm slice
// blocks [256,320): Wq/Wv -> bf16 tiles [ot][kc][m]
__global__ __launch_bounds__(768) void k_pre(const float* __restrict__ x,
                                             const float* __restrict__ Wq,
                                             const float* __restrict__ Wv,
                                             short8* __restrict__ Wqt,
                                             short8* __restrict__ Wvt,
                                             unsigned* __restrict__ FQm,
                                             float* __restrict__ Fg) {
    __shared__ float qa[HW];         // 36 KB |x|
    __shared__ float cs[96][2];
    __shared__ float Gp[8][96][5];
    __shared__ float Gs[96][6];
    __shared__ float red[24];
    __shared__ float s_mn, s_ptp;
    int bid = blockIdx.x, t = threadIdx.x;

    if (bid >= 256) {                // weight-conversion blocks
        int widx = bid - 256;        // 0..63
        if (t < 256) {
            const float* src = (widx >= 32) ? Wv : Wq;
            short8* dst = (widx >= 32) ? Wvt : Wqt;
            int cidx = (widx & 31) * 256 + t;             // 0..8191
            int ot = cidx >> 11, kc = (cidx >> 6) & 31, m = cidx & 63;
            const float* s = src + (ot * 64 + m) * 256 + kc * 8;
            short8 v;
            #pragma unroll
            for (int e = 0; e < 8; ++e) v[e] = (short)f2bf(s[e]);
            dst[cidx] = v;
        }
        return;
    }

    int c = bid;
    if (t < 96) FQm[c * 96 + t] = 0u;   // zero FQm (24576 words over 256 blocks)
    const float* xp = x + c * HW;
    if (t < 96) { float a = TWO_PI * (float)t / 96.0f; cs[t][0] = cosf(a); cs[t][1] = sinf(a); }
    float lo = 1e30f, hi = 0.f;
    #pragma unroll
    for (int i = 0; i < 12; ++i) {
        float a = fabsf(xp[t + i * 768]);
        qa[t + i * 768] = a;
        lo = fminf(lo, a);
        hi = fmaxf(hi, a);
    }
    #pragma unroll
    for (int d = 32; d; d >>= 1) {
        lo = fminf(lo, __shfl_xor(lo, d, 64));
        hi = fmaxf(hi, __shfl_xor(hi, d, 64));
    }
    if ((t & 63) == 0) { red[t >> 6] = lo; red[12 + (t >> 6)] = hi; }
    __syncthreads();
    if (t == 0) {
        lo = red[0]; hi = red[12];
        #pragma unroll
        for (int i = 1; i < 12; ++i) { lo = fminf(lo, red[i]); hi = fmaxf(hi, red[12 + i]); }
        s_mn = lo; s_ptp = hi - lo;
    }
    __syncthreads();
    float mn = s_mn, ptp = s_ptp;

    // Phase A: thread (xx = t%96, h = t/96) sums 12 rows of the column DFT from LDS
    {
        int xx = t % 96, h = t / 96;
        float g0r = 0, g0i = 0, g1r = 0, g1i = 0, g2 = 0;
        for (int y = h * 12; y < h * 12 + 12; ++y) {
            float q = floorf(255.0f * (qa[y * 96 + xx] - mn) / ptp);
            float c1 = cs[y][0], s1 = cs[y][1];
            float c2 = c1 * c1 - s1 * s1, s2 = 2.0f * c1 * s1;
            g0r += q * c2; g0i += q * s2;   // k=-2: e^{+2iθ}
            g1r += q * c1; g1i += q * s1;   // k=-1: e^{+iθ}
            g2  += q;                       // k=0
        }
        Gp[h][xx][0] = g0r; Gp[h][xx][1] = g0i;
        Gp[h][xx][2] = g1r; Gp[h][xx][3] = g1i;
        Gp[h][xx][4] = g2;
    }
    __syncthreads();
    if (t < 96) {
        #pragma unroll
        for (int j = 0; j < 5; ++j) {
            float s = 0.f;
            #pragma unroll
            for (int h = 0; h < 8; ++h) s += Gp[h][t][j];
            Gs[t][j] = s;
        }
        Gs[t][5] = 0.f;
    }
    __syncthreads();
    if (t < 64) {
        int coef = t >> 2, qq = t & 3;
        int ky = coef >> 2, kx = coef & 3;
        float fr = 0, fi = 0;
        for (int xx = qq * 24; xx < qq * 24 + 24; ++xx) {
            float c1 = cs[xx][0], s1 = cs[xx][1];
            float er, ei;
            if (kx == 0)      { er = c1 * c1 - s1 * s1; ei = 2.0f * c1 * s1; }
            else if (kx == 1) { er = c1; ei = s1; }
            else if (kx == 2) { er = 1.f; ei = 0.f; }
            else              { er = c1; ei = -s1; }
            float gr, gi;
            if (ky == 0)      { gr = Gs[xx][0]; gi = Gs[xx][1]; }
            else if (ky == 1) { gr = Gs[xx][2]; gi = Gs[xx][3]; }
            else if (ky == 2) { gr = Gs[xx][4]; gi = 0.f; }
            else              { gr = Gs[xx][2]; gi = -Gs[xx][3]; }
            fr += gr * er - gi * ei;
            fi += gr * ei + gi * er;
        }
        fr += __shfl_xor(fr, 1, 64); fr += __shfl_xor(fr, 2, 64);
        fi += __shfl_xor(fi, 1, 64); fi += __shfl_xor(fi, 2, 64);
        if (qq == 0) {
            Fg[c * 32 + 2 * coef]     = fr;
            Fg[c * 32 + 2 * coef + 1] = fi;
        }
    }
}

// ---------------- K_gemmQ: grid (144). ALL 4 ot tiles in one block — Rs/Bs synthesized ONCE,
// T-table (aliased on dead As region) kills per-element sincos; As reg-prefetched per ot;
// column-max accumulated in registers; 512 atomics/block -> FQm.
__global__ __launch_bounds__(256) void k_gemmQ(const short8* __restrict__ Wqt,
                                               const float* __restrict__ Fg,
                                               const float* __restrict__ bq,
                                               unsigned* __restrict__ FQm) {
    __shared__ short8 As[2048];     // 32 KB [kc][m]  (T-table aliases until MFMA loop)
    __shared__ short8 Bs[2048];     // 32 KB [kc][n]
    __shared__ float Rs[2048][2];   // 16 KB (fq aliases it after B-synth)
    float (*fq)[64] = (float (*)[64])Rs;   // 8x64 = 2 KB staging for atomic combine
    float (*Ts)[9]  = (float (*)[9])As;    // 64x9 floats = 2.25 KB, dead before MFMA loop
    int tid = threadIdx.x;
    int pt_ = blockIdx.x;
    int p0 = pt_ * 64;

    int l = tid & 63, w = tid >> 6;
    int wr = w >> 1, wc = w & 1;
    int l15 = l & 15, quad = l >> 4;
    int abase = wr * 32 + l15;
    int bbase = wc * 32 + l15;

    // ---- issue As(ot=0) prefetch immediately; completes during synthesis ----
    short8 areg[8];
    #pragma unroll
    for (int i = 0; i < 8; ++i) areg[i] = Wqt[i * 256 + tid];

    int y0 = p0 / 96;
    // T-table: 64 distinct xx values for this block's p-range (identical cosf bits)
    if (tid < 64) {
        int xx = (p0 + tid) % 96;
        float axv = TWO_PI * (float)xx / 96.0f;
        float cxv = cosf(axv), sxv = sinf(axv);
        float cx2 = cxv * cxv - sxv * sxv, sx2 = 2.f * cxv * sxv;
        Ts[tid][0] = cx2;  Ts[tid][1] = cxv;  Ts[tid][2] = 1.f; Ts[tid][3] = cxv;
        Ts[tid][4] = -sx2; Ts[tid][5] = -sxv; Ts[tid][6] = 0.f; Ts[tid][7] = sxv;
    }
    // R[c][yi][kx] = sum_ky F[c][ky][kx] * U[ky](y0+yi)
    {
        int yi = (tid >> 2) & 1, kx = tid & 3, cb = tid >> 3;
        float ay = TWO_PI * (float)(y0 + yi) / 96.0f;
        float cyv = cosf(ay), syv = sinf(ay);
        float cy2 = cyv * cyv - syv * syv, sy2 = 2.f * cyv * syv;
        float Ur[4] = { cy2, cyv, 1.f, cyv };
        float Ui[4] = { -sy2, -syv, 0.f, syv };
        #pragma unroll
        for (int i = 0; i < 8; ++i) {
            int cc = cb + i * 32;
            float rr = 0.f, ri = 0.f;
            #pragma unroll
            for (int ky = 0; ky < 4; ++ky) {
                float fr = Fg[cc * 32 + 2 * (ky * 4 + kx)];
                float fi = Fg[cc * 32 + 2 * (ky * 4 + kx) + 1];
                rr += fr * Ur[ky] - fi * Ui[ky];
                ri += fr * Ui[ky] + fi * Ur[ky];
            }
            Rs[cc * 8 + yi * 4 + kx][0] = rr;
            Rs[cc * 8 + yi * 4 + kx][1] = ri;
        }
    }
    __syncthreads();   // Rs + Ts ready
    // Bs[kc][n] = f2bf(|sum_kx R[c][yi(n)][kx] * T[kx](x(n))| / 9216)  — ONCE
    const float inv = 1.0f / 9216.0f;
    #pragma unroll
    for (int i = 0; i < 8; ++i) {
        int si = i * 256 + tid;
        int kcg = si >> 6, n = si & 63;
        int p = p0 + n;
        int y = p / 96;
        int yi = y - y0;
        float Tr[4], Ti[4];
        #pragma unroll
        for (int j = 0; j < 4; ++j) { Tr[j] = Ts[n][j]; Ti[j] = Ts[n][4 + j]; }
        short8 vv;
        #pragma unroll
        for (int e = 0; e < 8; ++e) {
            int rb = (kcg * 8 + e) * 8 + yi * 4;
            float ar = 0.f, ai = 0.f;
            #pragma unroll
            for (int kx = 0; kx < 4; ++kx) {
                float rr = Rs[rb + kx][0], ri = Rs[rb + kx][1];
                ar += rr * Tr[kx] - ri * Ti[kx];
                ai += rr * Ti[kx] + ri * Tr[kx];
            }
            vv[e] = (short)f2bf(sqrtf(ar * ar + ai * ai) * inv);
        }
        Bs[si] = vv;
    }
    __syncthreads();   // Bs ready; Rs and Ts dead from here (fq / As may alias)

    float vmax[2][4];
    #pragma unroll
    for (int ni = 0; ni < 2; ++ni)
        #pragma unroll
        for (int r = 0; r < 4; ++r) vmax[ni][r] = -3.0e38f;

    #pragma unroll
    for (int ot = 0; ot < 4; ++ot) {
        #pragma unroll
        for (int i = 0; i < 8; ++i) As[i * 256 + tid] = areg[i];
        __syncthreads();
        if (ot < 3) {          // prefetch next As tile; L2-hot, hides under MFMA
            #pragma unroll
            for (int i = 0; i < 8; ++i) areg[i] = Wqt[(ot + 1) * 2048 + i * 256 + tid];
        }
        f32x4 acc[2][2] = {};
        #pragma unroll
        for (int s = 0; s < 8; ++s) {
            int kc = s * 4 + quad;
            short8 a0 = As[kc * 64 + abase];
            short8 a1 = As[kc * 64 + abase + 16];
            short8 b0 = Bs[kc * 64 + bbase];
            short8 b1 = Bs[kc * 64 + bbase + 16];
            acc[0][0] = __builtin_amdgcn_mfma_f32_16x16x32_bf16(a0, b0, acc[0][0], 0, 0, 0);
            acc[0][1] = __builtin_amdgcn_mfma_f32_16x16x32_bf16(a0, b1, acc[0][1], 0, 0, 0);
            acc[1][0] = __builtin_amdgcn_mfma_f32_16x16x32_bf16(a1, b0, acc[1][0], 0, 0, 0);
            acc[1][1] = __builtin_amdgcn_mfma_f32_16x16x32_bf16(a1, b1, acc[1][1], 0, 0, 0);
        }
        // C/D layout: col = lane&15, row = quad*4 + reg; o&7 independent of ot/wr/mi
        #pragma unroll
        for (int ni = 0; ni < 2; ++ni) {
            #pragma unroll
            for (int r = 0; r < 4; ++r) {
                int o_lo = ot * 64 + wr * 32 + quad * 4 + r;
                float v = fmaxf(acc[0][ni][r] + bq[o_lo], acc[1][ni][r] + bq[o_lo + 16]);
                vmax[ni][r] = fmaxf(vmax[ni][r], v);
            }
        }
        __syncthreads();       // all waves done reading As before next overwrite
    }

    // fold lane^32 (quad <-> quad+2 pairs share o&7), then wr pairs via LDS
    #pragma unroll
    for (int ni = 0; ni < 2; ++ni)
        #pragma unroll
        for (int r = 0; r < 4; ++r)
            vmax[ni][r] = fmaxf(vmax[ni][r], __shfl_xor(vmax[ni][r], 32, 64));
    if (wr == 0 && quad < 2) {
        #pragma unroll
        for (int ni = 0; ni < 2; ++ni)
            #pragma unroll
            for (int r = 0; r < 4; ++r)
                fq[quad * 4 + r][wc * 32 + ni * 16 + l15] = vmax[ni][r];
    }
    __syncthreads();
    if (wr == 1 && quad < 2) {
        #pragma unroll
        for (int ni = 0; ni < 2; ++ni) {
            #pragma unroll
            for (int r = 0; r < 4; ++r) {
                int row = quad * 4 + r;
                int col = wc * 32 + ni * 16 + l15;
                float v = fmaxf(vmax[ni][r], fq[row][col]);
                int p = p0 + col;
                int k = row * HW + p;
                if (k >= CW) k -= CW;
                if (k >= CW) k -= CW;
                unsigned u = __float_as_uint(v);
                unsigned key = (u & 0x80000000u) ? ~u : (u | 0x80000000u);
                atomicMax(&FQm[k], key);
            }
        }
    }
}

// ---------------- K_gemmV: grid (144, 2). ot-pair {2y,2y+1} folded: Bs gathered ONCE;
// mask fused into epilogue (FQm complete — stream-ordered after k_gemmQ). 64 KB LDS.
__device__ inline float mdecode(unsigned key) {
    unsigned ub = (key & 0x80000000u) ? (key ^ 0x80000000u) : ~key;
    return __uint_as_float(ub);
}
__global__ __launch_bounds__(256) void k_gemmV(const short8* __restrict__ Wvt,
                                               const float* __restrict__ bv,
                                               const float* __restrict__ x,
                                               const unsigned* __restrict__ FQm,
                                               float* __restrict__ out) {
    __shared__ short8 As[2048];     // 32 KB [kc][m]
    __shared__ short8 Bs[2048];     // 32 KB [kc][n]
    int tid = threadIdx.x;
    int pt_ = blockIdx.x;
    int yv = blockIdx.y;            // 0..1 -> ot in {2yv, 2yv+1}
    int p0 = pt_ * 64;

    int l = tid & 63, w = tid >> 6;
    int wr = w >> 1, wc = w & 1;
    int l15 = l & 15, quad = l >> 4;
    int abase = wr * 32 + l15;
    int bbase = wc * 32 + l15;

    short8 areg[8];
    #pragma unroll
    for (int i = 0; i < 8; ++i) areg[i] = Wvt[(yv * 2) * 2048 + i * 256 + tid];

    // Bs[KC][n][e] = f2bf(x[(KC*8+e)*HW + p0+n]) — per-wave coalesced gather, ONCE per block
    #pragma unroll
    for (int i = 0; i < 8; ++i) {
        int si = i * 256 + tid;
        int KC = si >> 6, n = si & 63;
        const float* xb = x + (size_t)(KC * 8) * HW + p0 + n;
        short8 v;
        #pragma unroll
        for (int e = 0; e < 8; ++e) v[e] = (short)f2bf(xb[(size_t)e * HW]);
        Bs[si] = v;
    }

    // mask decode — independent of ot, hoisted; FQm is L2-resident
    float msk[2][4];
    #pragma unroll
    for (int ni = 0; ni < 2; ++ni) {
        #pragma unroll
        for (int r = 0; r < 4; ++r) {
            int row = (quad * 4 + r) & 7;
            int p = p0 + wc * 32 + ni * 16 + l15;
            int k = row * HW + p;
            if (k >= CW) k -= CW;
            if (k >= CW) k -= CW;
            msk[ni][r] = mdecode(FQm[k]);
        }
    }

    #pragma unroll
    for (int j = 0; j < 2; ++j) {
        int ot = yv * 2 + j;
        #pragma unroll
        for (int i = 0; i < 8; ++i) As[i * 256 + tid] = areg[i];
        __syncthreads();            // As stored (and Bs gathered, first iter)
        if (j == 0) {               // prefetch second tile; hides under MFMA
            #pragma unroll
            for (int i = 0; i < 8; ++i) areg[i] = Wvt[(yv * 2 + 1) * 2048 + i * 256 + tid];
        }
        f32x4 acc[2][2] = {};
        #pragma unroll
        for (int s = 0; s < 8; ++s) {
            int kc = s * 4 + quad;
            short8 a0 = As[kc * 64 + abase];
            short8 a1 = As[kc * 64 + abase + 16];
            short8 b0 = Bs[kc * 64 + bbase];
            short8 b1 = Bs[kc * 64 + bbase + 16];
            acc[0][0] = __builtin_amdgcn_mfma_f32_16x16x32_bf16(a0, b0, acc[0][0], 0, 0, 0);
            acc[0][1] = __builtin_amdgcn_mfma_f32_16x16x32_bf16(a0, b1, acc[0][1], 0, 0, 0);
            acc[1][0] = __builtin_amdgcn_mfma_f32_16x16x32_bf16(a1, b0, acc[1][0], 0, 0, 0);
            acc[1][1] = __builtin_amdgcn_mfma_f32_16x16x32_bf16(a1, b1, acc[1][1], 0, 0, 0);
        }
        // C/D layout: col = lane&15, row = quad*4 + reg.  out = (V+bv)*(1+mask)
        #pragma unroll
        for (int mi = 0; mi < 2; ++mi) {
            #pragma unroll
            for (int ni = 0; ni < 2; ++ni) {
                #pragma unroll
                for (int r = 0; r < 4; ++r) {
                    int o = ot * 64 + wr * 32 + mi * 16 + quad * 4 + r;
                    int p = p0 + wc * 32 + ni * 16 + l15;
                    out[(size_t)o * HW + p] = (acc[mi][ni][r] + bv[o]) * (1.0f + msk[ni][r]);
                }
            }
        }
        __syncthreads();            // done reading As before overwrite
    }
}

extern "C" void kernel_launch(void* const* d_in, const int* in_sizes, int n_in,
                              void* d_out, int out_size, void* d_ws, size_t ws_size,
                              hipStream_t stream) {
    const float* fuse = (const float*)d_in[0];
    const float* Wq   = (const float*)d_in[1];
    const float* bq   = (const float*)d_in[2];
    // d_in[3]=Wk, d_in[4]=bk dead for B=1 (softmax over batch axis of size 1 == 1)
    const float* Wv   = (const float*)d_in[5];
    const float* bv   = (const float*)d_in[6];
    float* out = (float*)d_out;

    char* ws = (char*)d_ws;
    unsigned* FQm = (unsigned*)(ws);            //  98304 B (zeroed by k_pre)
    float*    Fg  = (float*)(ws + 98304);       //  32768 B
    short8*   Wqt = (short8*)(ws + 131072);     // 131072 B
    short8*   Wvt = (short8*)(ws + 262144);     // 131072 B

    k_pre<<<320, 768, 0, stream>>>(fuse, Wq, Wv, Wqt, Wvt, FQm, Fg);
    k_gemmQ<<<144, 256, 0, stream>>>(Wqt, Fg, bq, FQm);
    k_gemmV<<<dim3(144, 2), 256, 0, stream>>>(Wvt, bv, fuse, FQm, out);
}

// Round 8
// 100.918 us; speedup vs baseline: 1.1109x; 1.0258x over previous
//
#include <hip/hip_runtime.h>
#include <math.h>

#define CCH 256
#define HW  9216
#define CW  24576
#define TWO_PI 6.28318530717958647692f

typedef __attribute__((ext_vector_type(8))) short short8;
typedef __attribute__((ext_vector_type(4))) float f32x4;

__device__ inline unsigned short f2bf(float f) {
    unsigned u = __float_as_uint(f);
    unsigned r = (u + 0x7FFFu + ((u >> 16) & 1u)) >> 16;   // RNE
    return (unsigned short)r;
}

// ---------------- K_pre: fused {per-channel DFT + FQm zero} and {weight conversion} ----------------
// blocks [0,256):  channel c = bid: |x| minmax + 16 DFT coefficients -> Fg; zero FQm slice
// blocks [256,320): Wq/Wv -> bf16 tiles [ot][kc][m]
__global__ __launch_bounds__(768) void k_pre(const float* __restrict__ x,
                                             const float* __restrict__ Wq,
                                             const float* __restrict__ Wv,
                                             short8* __restrict__ Wqt,
                                             short8* __restrict__ Wvt,
                                             unsigned* __restrict__ FQm,
                                             float* __restrict__ Fg) {
    __shared__ float qa[HW];         // 36 KB |x|
    __shared__ float cs[96][2];
    __shared__ float Gp[8][96][5];
    __shared__ float Gs[96][6];
    __shared__ float red[24];
    __shared__ float s_mn, s_ptp;
    int bid = blockIdx.x, t = threadIdx.x;

    if (bid >= 256) {                // weight-conversion blocks
        int widx = bid - 256;        // 0..63
        if (t < 256) {
            const float* src = (widx >= 32) ? Wv : Wq;
            short8* dst = (widx >= 32) ? Wvt : Wqt;
            int cidx = (widx & 31) * 256 + t;             // 0..8191
            int ot = cidx >> 11, kc = (cidx >> 6) & 31, m = cidx & 63;
            const float* s = src + (ot * 64 + m) * 256 + kc * 8;
            short8 v;
            #pragma unroll
            for (int e = 0; e < 8; ++e) v[e] = (short)f2bf(s[e]);
            dst[cidx] = v;
        }
        return;
    }

    int c = bid;
    if (t < 96) FQm[c * 96 + t] = 0u;   // zero FQm (24576 words over 256 blocks)
    const float* xp = x + c * HW;
    if (t < 96) { float a = TWO_PI * (float)t / 96.0f; cs[t][0] = cosf(a); cs[t][1] = sinf(a); }
    float lo = 1e30f, hi = 0.f;
    #pragma unroll
    for (int i = 0; i < 12; ++i) {
        float a = fabsf(xp[t + i * 768]);
        qa[t + i * 768] = a;
        lo = fminf(lo, a);
        hi = fmaxf(hi, a);
    }
    #pragma unroll
    for (int d = 32; d; d >>= 1) {
        lo = fminf(lo, __shfl_xor(lo, d, 64));
        hi = fmaxf(hi, __shfl_xor(hi, d, 64));
    }
    if ((t & 63) == 0) { red[t >> 6] = lo; red[12 + (t >> 6)] = hi; }
    __syncthreads();
    if (t == 0) {
        lo = red[0]; hi = red[12];
        #pragma unroll
        for (int i = 1; i < 12; ++i) { lo = fminf(lo, red[i]); hi = fmaxf(hi, red[12 + i]); }
        s_mn = lo; s_ptp = hi - lo;
    }
    __syncthreads();
    float mn = s_mn, ptp = s_ptp;

    // Phase A: thread (xx = t%96, h = t/96) sums 12 rows of the column DFT from LDS
    {
        int xx = t % 96, h = t / 96;
        float g0r = 0, g0i = 0, g1r = 0, g1i = 0, g2 = 0;
        for (int y = h * 12; y < h * 12 + 12; ++y) {
            float q = floorf(255.0f * (qa[y * 96 + xx] - mn) / ptp);
            float c1 = cs[y][0], s1 = cs[y][1];
            float c2 = c1 * c1 - s1 * s1, s2 = 2.0f * c1 * s1;
            g0r += q * c2; g0i += q * s2;   // k=-2: e^{+2iθ}
            g1r += q * c1; g1i += q * s1;   // k=-1: e^{+iθ}
            g2  += q;                       // k=0
        }
        Gp[h][xx][0] = g0r; Gp[h][xx][1] = g0i;
        Gp[h][xx][2] = g1r; Gp[h][xx][3] = g1i;
        Gp[h][xx][4] = g2;
    }
    __syncthreads();
    if (t < 96) {
        #pragma unroll
        for (int j = 0; j < 5; ++j) {
            float s = 0.f;
            #pragma unroll
            for (int h = 0; h < 8; ++h) s += Gp[h][t][j];
            Gs[t][j] = s;
        }
        Gs[t][5] = 0.f;
    }
    __syncthreads();
    if (t < 64) {
        int coef = t >> 2, qq = t & 3;
        int ky = coef >> 2, kx = coef & 3;
        float fr = 0, fi = 0;
        for (int xx = qq * 24; xx < qq * 24 + 24; ++xx) {
            float c1 = cs[xx][0], s1 = cs[xx][1];
            float er, ei;
            if (kx == 0)      { er = c1 * c1 - s1 * s1; ei = 2.0f * c1 * s1; }
            else if (kx == 1) { er = c1; ei = s1; }
            else if (kx == 2) { er = 1.f; ei = 0.f; }
            else              { er = c1; ei = -s1; }
            float gr, gi;
            if (ky == 0)      { gr = Gs[xx][0]; gi = Gs[xx][1]; }
            else if (ky == 1) { gr = Gs[xx][2]; gi = Gs[xx][3]; }
            else if (ky == 2) { gr = Gs[xx][4]; gi = 0.f; }
            else              { gr = Gs[xx][2]; gi = -Gs[xx][3]; }
            fr += gr * er - gi * ei;
            fi += gr * ei + gi * er;
        }
        fr += __shfl_xor(fr, 1, 64); fr += __shfl_xor(fr, 2, 64);
        fi += __shfl_xor(fi, 1, 64); fi += __shfl_xor(fi, 2, 64);
        if (qq == 0) {
            Fg[c * 32 + 2 * coef]     = fr;
            Fg[c * 32 + 2 * coef + 1] = fi;
        }
    }
}

// ---------------- K_gemmQ: grid (144) x 512 threads (8 waves). ALL 4 ot tiles in one block.
// 8-wave split halves every per-thread serial chain (R-synth, B-synth, staging) and doubles
// latency-hiding TLP. Wave w: row-half rw=w>>2, col-quarter cw=w&3 (2 MFMA tiles/wave).
// Colmax: in-thread acc pair + shfl^32 + cross-rw LDS combine -> 512 atomicMax/block.
__global__ __launch_bounds__(512) void k_gemmQ(const short8* __restrict__ Wqt,
                                               const float* __restrict__ Fg,
                                               const float* __restrict__ bq,
                                               unsigned* __restrict__ FQm) {
    __shared__ short8 As[2048];     // 32 KB [kc][m]  (T-table aliases until MFMA loop)
    __shared__ short8 Bs[2048];     // 32 KB [kc][n]
    __shared__ float Rs[2048][2];   // 16 KB (fq aliases it after B-synth)
    float (*fq)[64] = (float (*)[64])Rs;   // 8x64 = 2 KB staging for cross-rw combine
    float (*Ts)[9]  = (float (*)[9])As;    // 64x9 floats = 2.25 KB, dead before MFMA loop
    int tid = threadIdx.x;
    int pt_ = blockIdx.x;
    int p0 = pt_ * 64;

    int l = tid & 63, w = tid >> 6;
    int rw = w >> 2, cw = w & 3;
    int l15 = l & 15, quad = l >> 4;
    int abase = rw * 32 + l15;
    int bbase = cw * 16 + l15;

    // ---- issue As(ot=0) prefetch immediately; completes during synthesis ----
    short8 areg[4];
    #pragma unroll
    for (int i = 0; i < 4; ++i) areg[i] = Wqt[i * 512 + tid];

    int y0 = p0 / 96;
    // T-table: 64 distinct xx values for this block's p-range (identical cosf bits)
    if (tid < 64) {
        int xx = (p0 + tid) % 96;
        float axv = TWO_PI * (float)xx / 96.0f;
        float cxv = cosf(axv), sxv = sinf(axv);
        float cx2 = cxv * cxv - sxv * sxv, sx2 = 2.f * cxv * sxv;
        Ts[tid][0] = cx2;  Ts[tid][1] = cxv;  Ts[tid][2] = 1.f; Ts[tid][3] = cxv;
        Ts[tid][4] = -sx2; Ts[tid][5] = -sxv; Ts[tid][6] = 0.f; Ts[tid][7] = sxv;
    }
    // R[c][yi][kx] = sum_ky F[c][ky][kx] * U[ky](y0+yi) — 512 threads, 4 cc each
    {
        int yi = (tid >> 2) & 1, kx = tid & 3, cb = tid >> 3;   // cb 0..63
        float ay = TWO_PI * (float)(y0 + yi) / 96.0f;
        float cyv = cosf(ay), syv = sinf(ay);
        float cy2 = cyv * cyv - syv * syv, sy2 = 2.f * cyv * syv;
        float Ur[4] = { cy2, cyv, 1.f, cyv };
        float Ui[4] = { -sy2, -syv, 0.f, syv };
        #pragma unroll
        for (int i = 0; i < 4; ++i) {
            int cc = cb + i * 64;
            float rr = 0.f, ri = 0.f;
            #pragma unroll
            for (int ky = 0; ky < 4; ++ky) {
                float fr = Fg[cc * 32 + 2 * (ky * 4 + kx)];
                float fi = Fg[cc * 32 + 2 * (ky * 4 + kx) + 1];
                rr += fr * Ur[ky] - fi * Ui[ky];
                ri += fr * Ui[ky] + fi * Ur[ky];
            }
            Rs[cc * 8 + yi * 4 + kx][0] = rr;
            Rs[cc * 8 + yi * 4 + kx][1] = ri;
        }
    }
    __syncthreads();   // Rs + Ts ready
    // Bs[kc][n] = f2bf(|sum_kx R[c][yi(n)][kx] * T[kx](x(n))| / 9216) — 4 si-iters/thread
    const float inv = 1.0f / 9216.0f;
    #pragma unroll
    for (int i = 0; i < 4; ++i) {
        int si = i * 512 + tid;
        int kcg = si >> 6, n = si & 63;
        int p = p0 + n;
        int y = p / 96;
        int yi = y - y0;
        float Tr[4], Ti[4];
        #pragma unroll
        for (int j = 0; j < 4; ++j) { Tr[j] = Ts[n][j]; Ti[j] = Ts[n][4 + j]; }
        short8 vv;
        #pragma unroll
        for (int e = 0; e < 8; ++e) {
            int rb = (kcg * 8 + e) * 8 + yi * 4;
            float ar = 0.f, ai = 0.f;
            #pragma unroll
            for (int kx = 0; kx < 4; ++kx) {
                float rr = Rs[rb + kx][0], ri = Rs[rb + kx][1];
                ar += rr * Tr[kx] - ri * Ti[kx];
                ai += rr * Ti[kx] + ri * Tr[kx];
            }
            vv[e] = (short)f2bf(sqrtf(ar * ar + ai * ai) * inv);
        }
        Bs[si] = vv;
    }
    __syncthreads();   // Bs ready; Rs and Ts dead from here (fq / As may alias)

    float vmax[4];
    #pragma unroll
    for (int r = 0; r < 4; ++r) vmax[r] = -3.0e38f;

    #pragma unroll
    for (int ot = 0; ot < 4; ++ot) {
        #pragma unroll
        for (int i = 0; i < 4; ++i) As[i * 512 + tid] = areg[i];
        __syncthreads();
        if (ot < 3) {          // prefetch next As tile; L2-hot, hides under MFMA
            #pragma unroll
            for (int i = 0; i < 4; ++i) areg[i] = Wqt[(ot + 1) * 2048 + i * 512 + tid];
        }
        f32x4 acc[2] = {};     // acc[mi]: rows rw*32 + mi*16 + quad*4+r, cols cw*16+l15
        #pragma unroll
        for (int s = 0; s < 8; ++s) {
            int kc = s * 4 + quad;
            short8 a0 = As[kc * 64 + abase];
            short8 a1 = As[kc * 64 + abase + 16];
            short8 b0 = Bs[kc * 64 + bbase];
            acc[0] = __builtin_amdgcn_mfma_f32_16x16x32_bf16(a0, b0, acc[0], 0, 0, 0);
            acc[1] = __builtin_amdgcn_mfma_f32_16x16x32_bf16(a1, b0, acc[1], 0, 0, 0);
        }
        // C/D layout: col = lane&15, row = quad*4 + reg; o&7 independent of ot/rw/mi
        #pragma unroll
        for (int r = 0; r < 4; ++r) {
            int o_lo = ot * 64 + rw * 32 + quad * 4 + r;
            float v = fmaxf(acc[0][r] + bq[o_lo], acc[1][r] + bq[o_lo + 16]);
            vmax[r] = fmaxf(vmax[r], v);
        }
        __syncthreads();       // all waves done reading As before next overwrite
    }

    // fold lane^32 (quad <-> quad+2 pairs share o&7), then rw halves via LDS
    #pragma unroll
    for (int r = 0; r < 4; ++r)
        vmax[r] = fmaxf(vmax[r], __shfl_xor(vmax[r], 32, 64));
    if (rw == 0 && quad < 2) {
        #pragma unroll
        for (int r = 0; r < 4; ++r)
            fq[quad * 4 + r][cw * 16 + l15] = vmax[r];
    }
    __syncthreads();
    if (rw == 1 && quad < 2) {
        #pragma unroll
        for (int r = 0; r < 4; ++r) {
            int row = quad * 4 + r;
            int col = cw * 16 + l15;
            float v = fmaxf(vmax[r], fq[row][col]);
            int p = p0 + col;
            int k = row * HW + p;
            if (k >= CW) k -= CW;
            if (k >= CW) k -= CW;
            unsigned u = __float_as_uint(v);
            unsigned key = (u & 0x80000000u) ? ~u : (u | 0x80000000u);
            atomicMax(&FQm[k], key);
        }
    }
}

// ---------------- K_gemmV: grid (144, 2) x 512 threads (8 waves). ot-pair folded, Bs
// gathered once (4 si-iters/thread); mask fused into epilogue (stream-ordered after Q).
__device__ inline float mdecode(unsigned key) {
    unsigned ub = (key & 0x80000000u) ? (key ^ 0x80000000u) : ~key;
    return __uint_as_float(ub);
}
__global__ __launch_bounds__(512) void k_gemmV(const short8* __restrict__ Wvt,
                                               const float* __restrict__ bv,
                                               const float* __restrict__ x,
                                               const unsigned* __restrict__ FQm,
                                               float* __restrict__ out) {
    __shared__ short8 As[2048];     // 32 KB [kc][m]
    __shared__ short8 Bs[2048];     // 32 KB [kc][n]
    int tid = threadIdx.x;
    int pt_ = blockIdx.x;
    int yv = blockIdx.y;            // 0..1 -> ot in {2yv, 2yv+1}
    int p0 = pt_ * 64;

    int l = tid & 63, w = tid >> 6;
    int rw = w >> 2, cw = w & 3;
    int l15 = l & 15, quad = l >> 4;
    int abase = rw * 32 + l15;
    int bbase = cw * 16 + l15;

    short8 areg[4];
    #pragma unroll
    for (int i = 0; i < 4; ++i) areg[i] = Wvt[(yv * 2) * 2048 + i * 512 + tid];

    // Bs[KC][n][e] = f2bf(x[(KC*8+e)*HW + p0+n]) — per-wave coalesced gather, 4 iters
    #pragma unroll
    for (int i = 0; i < 4; ++i) {
        int si = i * 512 + tid;
        int KC = si >> 6, n = si & 63;
        const float* xb = x + (size_t)(KC * 8) * HW + p0 + n;
        short8 v;
        #pragma unroll
        for (int e = 0; e < 8; ++e) v[e] = (short)f2bf(xb[(size_t)e * HW]);
        Bs[si] = v;
    }

    // mask decode — independent of ot, hoisted; FQm is L2-resident
    float msk[4];
    #pragma unroll
    for (int r = 0; r < 4; ++r) {
        int row = (quad * 4 + r) & 7;
        int p = p0 + cw * 16 + l15;
        int k = row * HW + p;
        if (k >= CW) k -= CW;
        if (k >= CW) k -= CW;
        msk[r] = mdecode(FQm[k]);
    }

    #pragma unroll
    for (int j = 0; j < 2; ++j) {
        int ot = yv * 2 + j;
        #pragma unroll
        for (int i = 0; i < 4; ++i) As[i * 512 + tid] = areg[i];
        __syncthreads();            // As stored (and Bs gathered, first iter)
        if (j == 0) {               // prefetch second tile; hides under MFMA
            #pragma unroll
            for (int i = 0; i < 4; ++i) areg[i] = Wvt[(yv * 2 + 1) * 2048 + i * 512 + tid];
        }
        f32x4 acc[2] = {};          // acc[mi]: rows rw*32 + mi*16 + quad*4+r, cols cw*16+l15
        #pragma unroll
        for (int s = 0; s < 8; ++s) {
            int kc = s * 4 + quad;
            short8 a0 = As[kc * 64 + abase];
            short8 a1 = As[kc * 64 + abase + 16];
            short8 b0 = Bs[kc * 64 + bbase];
            acc[0] = __builtin_amdgcn_mfma_f32_16x16x32_bf16(a0, b0, acc[0], 0, 0, 0);
            acc[1] = __builtin_amdgcn_mfma_f32_16x16x32_bf16(a1, b0, acc[1], 0, 0, 0);
        }
        // C/D layout: col = lane&15, row = quad*4 + reg.  out = (V+bv)*(1+mask)
        #pragma unroll
        for (int mi = 0; mi < 2; ++mi) {
            #pragma unroll
            for (int r = 0; r < 4; ++r) {
                int o = ot * 64 + rw * 32 + mi * 16 + quad * 4 + r;
                int p = p0 + cw * 16 + l15;
                out[(size_t)o * HW + p] = (acc[mi][r] + bv[o]) * (1.0f + msk[r]);
            }
        }
        __syncthreads();            // done reading As before overwrite
    }
}

extern "C" void kernel_launch(void* const* d_in, const int* in_sizes, int n_in,
                              void* d_out, int out_size, void* d_ws, size_t ws_size,
                              hipStream_t stream) {
    const float* fuse = (const float*)d_in[0];
    const float* Wq   = (const float*)d_in[1];
    const float* bq   = (const float*)d_in[2];
    // d_in[3]=Wk, d_in[4]=bk dead for B=1 (softmax over batch axis of size 1 == 1)
    const float* Wv   = (const float*)d_in[5];
    const float* bv   = (const float*)d_in[6];
    float* out = (float*)d_out;

    char* ws = (char*)d_ws;
    unsigned* FQm = (unsigned*)(ws);            //  98304 B (zeroed by k_pre)
    float*    Fg  = (float*)(ws + 98304);       //  32768 B
    short8*   Wqt = (short8*)(ws + 131072);     // 131072 B
    short8*   Wvt = (short8*)(ws + 262144);     // 131072 B

    k_pre<<<320, 768, 0, stream>>>(fuse, Wq, Wv, Wqt, Wvt, FQm, Fg);
    k_gemmQ<<<144, 512, 0, stream>>>(Wqt, Fg, bq, FQm);
    k_gemmV<<<dim3(144, 2), 512, 0, stream>>>(Wvt, bv, fuse, FQm, out);
}